// Round 3
// baseline (55.634 us; speedup 1.0000x reference)
//
#include <hip/hip_runtime.h>
#include <hip/hip_bf16.h>

typedef __attribute__((ext_vector_type(4))) float f32x4;
typedef __attribute__((ext_vector_type(8))) short short8;

#define NB 8192
#define ND 256
#define NK 32
#define PADF 520   // padded row stride (bf16 elems) for AcT/AqT: 1040B = 16B-aligned,
                   // 260 words/row == 4 banks mod 32 -> 16-row column reads conflict-free

static __device__ __forceinline__ unsigned short f2bf(float f) {
  return __builtin_bit_cast(unsigned short, __float2bfloat16(f));
}

static __device__ __forceinline__ f32x4 mfma_bf16(short8 a, short8 b, f32x4 c) {
  return __builtin_amdgcn_mfma_f32_16x16x32_bf16(a, b, c, 0, 0, 0);
}

// ---- kernel 0: fused prep ---------------------------------------------------
// blocks [0,2048)    : x fp32 -> bf16
// blocks [2048,2560) : Wcat = [W_mu; W_sig] -> bf16 [512][256]
// blocks [2560,2592) : Bc bf16 [32][512]: Bc[k][d]=exp(-lsc), Bc[k][256+d]=-2*mu_c*exp(-lsc)
//                      c3k[k]=sum mu_c^2*inv ; ckk[k]=sum lsc + c3k[k]
__global__ __launch_bounds__(256) void prep_k(const float4* __restrict__ x,
                                              ushort4* __restrict__ xb,
                                              const float* __restrict__ wmu,
                                              const float* __restrict__ wsig,
                                              __hip_bfloat16* __restrict__ wb,
                                              const float* __restrict__ mu_c,
                                              const float* __restrict__ lsc,
                                              __hip_bfloat16* __restrict__ Bc,
                                              float* __restrict__ c3k,
                                              float* __restrict__ ckk) {
  __shared__ float red1[4], red2[4];
  const int blk = blockIdx.x, tid = threadIdx.x;
  if (blk < 2048) {
    int i = blk * 256 + tid;
    float4 v = x[i];
    ushort4 o;
    o.x = f2bf(v.x); o.y = f2bf(v.y); o.z = f2bf(v.z); o.w = f2bf(v.w);
    xb[i] = o;
  } else if (blk < 2560) {
    int i = (blk - 2048) * 256 + tid;
    float v = (i < 65536) ? wmu[i] : wsig[i - 65536];
    wb[i] = __float2bfloat16(v);
  } else {
    int k = blk - 2560;
    int d = tid;
    float l = lsc[k * ND + d];
    float inv = __expf(-l);
    float mc = mu_c[k * ND + d];
    Bc[k * 512 + d]       = __float2bfloat16(inv);
    Bc[k * 512 + 256 + d] = __float2bfloat16(-2.f * mc * inv);
    float s1 = l, s2 = mc * mc * inv;
    #pragma unroll
    for (int sh = 32; sh; sh >>= 1) { s1 += __shfl_xor(s1, sh); s2 += __shfl_xor(s2, sh); }
    int lane = tid & 63, wv = tid >> 6;
    if (lane == 0) { red1[wv] = s1; red2[wv] = s2; }
    __syncthreads();
    if (tid == 0) {
      float t1 = red1[0] + red1[1] + red1[2] + red1[3];
      float t2 = red2[0] + red2[1] + red2[2] + red2[3];
      c3k[k] = t2;
      ckk[k] = t1 + t2;
    }
  }
}

// ---- kernel 1: fully fused GEMM1 + z + cluster GEMM + softmax --------------
// 256 blocks x 512 thr (8 waves); block owns 32 b-rows.
// Phase 1: C1[32 b][512 n] = x . Wcat^T, wave w covers n-slice [w*64,w*64+64),
//   A/B fragments read DIRECT from global (A is L1-resident, W is L2-resident).
//   n-interleave: tile-row rr -> Wcat row (rr&16?256:0) + w*32 + (rr>>5)*16 + (rr&15)
//   so frag nf: plane=nf&1 (mu/sig), d = w*32 + (nf>>1)*16 + (lane&15).
// Epilogue: z -> d_out; bf16 [z^2|z] -> AcT, [sq+mu^2|mu] -> AqT (LDS, padded).
// Phase 2: cluster GEMMs [32 b x 32 k], contraction K=512 split across 8 waves
//   (wave w: feature cols [w*64,w*64+64)), B=Bc from global (L2-hot).
//   8-way partial reduce via LDS atomics; then 16-lane-group softmax + loss.
__global__ __launch_bounds__(512) void fused_k(const __hip_bfloat16* __restrict__ xbf,
                                               const __hip_bfloat16* __restrict__ wbf,
                                               const float* __restrict__ bmu,
                                               const float* __restrict__ bsigv,
                                               const float* __restrict__ eps,
                                               const __hip_bfloat16* __restrict__ Bc,
                                               const float* __restrict__ c3k,
                                               const float* __restrict__ ckk,
                                               float* __restrict__ zout,
                                               float* __restrict__ part) {
  __shared__ __align__(16) unsigned short AcT[32][PADF];
  __shared__ __align__(16) unsigned short AqT[32][PADF];
  __shared__ float accR[2][32][32];
  __shared__ float piP[NK];
  __shared__ float gSum;

  const int tid = threadIdx.x;
  const int lane = tid & 63;
  const int w = tid >> 6;          // wave 0..7
  const int lrow = lane & 15;
  const int q = lane >> 4;         // quarter 0..3
  const int m0 = blockIdx.x * 32;

  {
    float* ar = (float*)accR;
    for (int i = tid; i < 2 * 32 * 32; i += 512) ar[i] = 0.f;
    if (tid < NK) piP[tid] = 0.f;
    if (tid == 0) gSum = 0.f;
  }

  // ---------------- phase 1: GEMM1 ----------------
  f32x4 acc[2][4];
  #pragma unroll
  for (int a = 0; a < 2; ++a)
    #pragma unroll
    for (int b = 0; b < 4; ++b) acc[a][b] = (f32x4){0.f, 0.f, 0.f, 0.f};

  const __hip_bfloat16* aB0 = xbf + (size_t)(m0 + lrow) * ND + q * 8;
  const __hip_bfloat16* aB1 = aB0 + 16 * ND;
  const __hip_bfloat16* bB[4];
  #pragma unroll
  for (int nf = 0; nf < 4; ++nf) {
    int wrow = (nf & 1) * 256 + w * 32 + (nf >> 1) * 16 + lrow;
    bB[nf] = wbf + (size_t)wrow * ND + q * 8;
  }

  #pragma unroll
  for (int ks = 0; ks < 8; ++ks) {
    const int kc = ks * 32;
    short8 a0 = *reinterpret_cast<const short8*>(aB0 + kc);
    short8 a1 = *reinterpret_cast<const short8*>(aB1 + kc);
    #pragma unroll
    for (int nf = 0; nf < 4; ++nf) {
      short8 bfv = *reinterpret_cast<const short8*>(bB[nf] + kc);
      acc[0][nf] = mfma_bf16(a0, bfv, acc[0][nf]);
      acc[1][nf] = mfma_bf16(a1, bfv, acc[1][nf]);
    }
  }

  // ---------------- epilogue 1: z + LDS deposit ----------------
  #pragma unroll
  for (int dp = 0; dp < 2; ++dp) {
    const int d = w * 32 + dp * 16 + lrow;
    const float bm = bmu[d], bs = bsigv[d];
    #pragma unroll
    for (int mf = 0; mf < 2; ++mf) {
      #pragma unroll
      for (int j = 0; j < 4; ++j) {
        const int bl = mf * 16 + q * 4 + j;
        const int b = m0 + bl;
        float muv = acc[mf][dp * 2][j] + bm;
        float lsv = acc[mf][dp * 2 + 1][j] + bs;
        float sq  = __expf(lsv);
        float e   = eps[(size_t)b * ND + d];
        float zv  = muv + sqrtf(sq) * e;
        zout[(size_t)b * ND + d] = zv;
        AcT[bl][d]       = f2bf(zv * zv);
        AcT[bl][256 + d] = f2bf(zv);
        AqT[bl][d]       = f2bf(sq + muv * muv);
        AqT[bl][256 + d] = f2bf(muv);
      }
    }
  }
  __syncthreads();

  // ---------------- phase 2: cluster GEMMs (K-split across waves) ----------
  f32x4 cc[2][2][2];   // [mat L/Q][m-frag][k-cluster-frag]
  #pragma unroll
  for (int a = 0; a < 2; ++a)
    #pragma unroll
    for (int b = 0; b < 2; ++b)
      #pragma unroll
      for (int c = 0; c < 2; ++c) cc[a][b][c] = (f32x4){0.f, 0.f, 0.f, 0.f};

  #pragma unroll
  for (int ks = 0; ks < 2; ++ks) {
    const int fc = w * 64 + ks * 32 + q * 8;
    short8 ac0 = *reinterpret_cast<const short8*>(&AcT[lrow][fc]);
    short8 ac1 = *reinterpret_cast<const short8*>(&AcT[16 + lrow][fc]);
    short8 aq0 = *reinterpret_cast<const short8*>(&AqT[lrow][fc]);
    short8 aq1 = *reinterpret_cast<const short8*>(&AqT[16 + lrow][fc]);
    short8 b0 = *reinterpret_cast<const short8*>(Bc + (size_t)lrow * 512 + fc);
    short8 b1 = *reinterpret_cast<const short8*>(Bc + (size_t)(16 + lrow) * 512 + fc);
    cc[0][0][0] = mfma_bf16(ac0, b0, cc[0][0][0]);
    cc[0][0][1] = mfma_bf16(ac0, b1, cc[0][0][1]);
    cc[0][1][0] = mfma_bf16(ac1, b0, cc[0][1][0]);
    cc[0][1][1] = mfma_bf16(ac1, b1, cc[0][1][1]);
    cc[1][0][0] = mfma_bf16(aq0, b0, cc[1][0][0]);
    cc[1][0][1] = mfma_bf16(aq0, b1, cc[1][0][1]);
    cc[1][1][0] = mfma_bf16(aq1, b0, cc[1][1][0]);
    cc[1][1][1] = mfma_bf16(aq1, b1, cc[1][1][1]);
  }

  #pragma unroll
  for (int mt = 0; mt < 2; ++mt)
    #pragma unroll
    for (int mfc = 0; mfc < 2; ++mfc)
      #pragma unroll
      for (int nfk = 0; nfk < 2; ++nfk) {
        const int k = nfk * 16 + lrow;
        #pragma unroll
        for (int j = 0; j < 4; ++j) {
          const int bl = mfc * 16 + q * 4 + j;
          atomicAdd(&accR[mt][bl][k], cc[mt][mfc][nfk][j]);
        }
      }
  __syncthreads();

  // ---------------- epilogue 2: softmax + loss partials ----------------
  {
    const int b = tid >> 4;       // 0..31
    const int kk = tid & 15;
    float L0 = accR[0][b][kk], L1 = accR[0][b][kk + 16];
    float Q0 = accR[1][b][kk], Q1 = accR[1][b][kk + 16];
    float l0 = -(L0 + c3k[kk]);
    float l1 = -(L1 + c3k[kk + 16]);
    float mx = fmaxf(l0, l1);
    #pragma unroll
    for (int s = 8; s; s >>= 1) mx = fmaxf(mx, __shfl_xor(mx, s));
    float p0 = __expf(l0 - mx), p1 = __expf(l1 - mx);
    float ps = p0 + p1;
    #pragma unroll
    for (int s = 8; s; s >>= 1) ps += __shfl_xor(ps, s);
    float pi0 = p0 / ps + 1e-10f;
    float pi1 = p1 / ps + 1e-10f;
    float g = pi0 * (Q0 + ckk[kk]) + pi1 * (Q1 + ckk[kk + 16]);
    #pragma unroll
    for (int s = 8; s; s >>= 1) g += __shfl_xor(g, s);
    atomicAdd(&piP[kk], pi0);
    atomicAdd(&piP[kk + 16], pi1);
    if (kk == 0) atomicAdd(&gSum, g);
  }
  __syncthreads();
  if (tid < NK) part[blockIdx.x * 33 + tid] = piP[tid];
  if (tid == NK) part[blockIdx.x * 33 + NK] = 0.5f * gSum;
}

// ---- kernel 2: final reduce ------------------------------------------------
__global__ void final_k(const float* __restrict__ part, float* __restrict__ out) {
  int lane = threadIdx.x;   // 1 block, 64 threads
  double acc = 0.0;
  if (lane < 33)
    for (int bk = 0; bk < 256; ++bk) acc += (double)part[bk * 33 + lane];
  double g = __shfl(acc, 32);
  double t = 0.0;
  if (lane < 32) {
    double mk = acc / (double)NB;
    t = mk * log(mk);
  }
  #pragma unroll
  for (int s = 16; s; s >>= 1) t += __shfl_xor(t, s);
  if (lane == 0) {
    out[NB * ND]     = (float)g;                 // batch_gaussian_loss
    out[NB * ND + 1] = (float)(t / (double)NK);  // batch_uniform_loss
  }
}

extern "C" void kernel_launch(void* const* d_in, const int* in_sizes, int n_in,
                              void* d_out, int out_size, void* d_ws, size_t ws_size,
                              hipStream_t stream) {
  const float* x    = (const float*)d_in[0];
  const float* eps  = (const float*)d_in[1];
  const float* wmu  = (const float*)d_in[2];
  const float* bmu  = (const float*)d_in[3];
  const float* wsig = (const float*)d_in[4];
  const float* bsig = (const float*)d_in[5];
  const float* mu_c = (const float*)d_in[6];
  const float* lsc  = (const float*)d_in[7];
  float* out = (float*)d_out;

  char* ws = (char*)d_ws;
  __hip_bfloat16* xbf = (__hip_bfloat16*)ws;                         // 4 MiB
  __hip_bfloat16* wbf = (__hip_bfloat16*)(ws + (4u << 20));          // 256 KiB
  __hip_bfloat16* Bc  = (__hip_bfloat16*)(ws + (4u << 20) + (256u << 10)); // 32 KiB
  float* c3k  = (float*)(ws + (4u << 20) + (288u << 10));            // 128 B
  float* ckk  = (float*)(ws + (4u << 20) + (288u << 10) + 256u);     // 128 B
  float* part = (float*)(ws + (4u << 20) + (288u << 10) + 512u);     // ~34 KiB

  prep_k<<<2592, 256, 0, stream>>>((const float4*)x, (ushort4*)xbf,
                                   wmu, wsig, wbf, mu_c, lsc, Bc, c3k, ckk);
  fused_k<<<256, 512, 0, stream>>>(xbf, wbf, bmu, bsig, eps, Bc, c3k, ckk, out, part);
  final_k<<<1, 64, 0, stream>>>(part, out);
}

// Round 4
// 46.878 us; speedup vs baseline: 1.1868x; 1.1868x over previous
//
#include <hip/hip_runtime.h>
#include <hip/hip_bf16.h>

typedef __attribute__((ext_vector_type(4))) float f32x4;
typedef __attribute__((ext_vector_type(8))) short short8;

#define NB 8192
#define ND 256
#define NK 32

static __device__ __forceinline__ unsigned short f2bf(float f) {
  return __builtin_bit_cast(unsigned short, __float2bfloat16(f));
}

static __device__ __forceinline__ f32x4 mfma_bf16(short8 a, short8 b, f32x4 c) {
  return __builtin_amdgcn_mfma_f32_16x16x32_bf16(a, b, c, 0, 0, 0);
}

// ---- kernel 0: fused prep ---------------------------------------------------
// blocks [0,2048)    : x fp32 -> bf16
// blocks [2048,2560) : Wcat = [W_mu; W_sig] -> bf16 [512][256]
// blocks [2560,2592) : Bc bf16 [32][512]: Bc[k][d]=exp(-lsc), Bc[k][256+d]=-2*mu_c*exp(-lsc)
//                      c3k[k]=sum mu_c^2*inv ; ckk[k]=sum lsc + c3k[k]
__global__ __launch_bounds__(256) void prep_k(const float4* __restrict__ x,
                                              ushort4* __restrict__ xb,
                                              const float* __restrict__ wmu,
                                              const float* __restrict__ wsig,
                                              __hip_bfloat16* __restrict__ wb,
                                              const float* __restrict__ mu_c,
                                              const float* __restrict__ lsc,
                                              __hip_bfloat16* __restrict__ Bc,
                                              float* __restrict__ c3k,
                                              float* __restrict__ ckk) {
  __shared__ float red1[4], red2[4];
  const int blk = blockIdx.x, tid = threadIdx.x;
  if (blk < 2048) {
    int i = blk * 256 + tid;
    float4 v = x[i];
    ushort4 o;
    o.x = f2bf(v.x); o.y = f2bf(v.y); o.z = f2bf(v.z); o.w = f2bf(v.w);
    xb[i] = o;
  } else if (blk < 2560) {
    int i = (blk - 2048) * 256 + tid;
    float v = (i < 65536) ? wmu[i] : wsig[i - 65536];
    wb[i] = __float2bfloat16(v);
  } else {
    int k = blk - 2560;
    int d = tid;
    float l = lsc[k * ND + d];
    float inv = __expf(-l);
    float mc = mu_c[k * ND + d];
    Bc[k * 512 + d]       = __float2bfloat16(inv);
    Bc[k * 512 + 256 + d] = __float2bfloat16(-2.f * mc * inv);
    float s1 = l, s2 = mc * mc * inv;
    #pragma unroll
    for (int sh = 32; sh; sh >>= 1) { s1 += __shfl_xor(s1, sh); s2 += __shfl_xor(s2, sh); }
    int lane = tid & 63, wv = tid >> 6;
    if (lane == 0) { red1[wv] = s1; red2[wv] = s2; }
    __syncthreads();
    if (tid == 0) {
      float t1 = red1[0] + red1[1] + red1[2] + red1[3];
      float t2 = red2[0] + red2[1] + red2[2] + red2[3];
      c3k[k] = t2;
      ckk[k] = t1 + t2;
    }
  }
}

// ---- kernel 1: GEMM1 + z + cluster-A construction (no LDS, no barriers) ----
// grid (128,8), 256 thr = 4 waves. Wave owns 16 b-rows (m0=blkx*64+wv*16),
// block d-range 32 (d0=blky*32). Wcat-row for frag nf:
//   (nf>>1)*256 + d0 + (nf&1)*16 + lrow   -> acc[0,1]=mu d-pair, acc[2,3]=sig
// A/W fragments read DIRECT from global: each load instr covers 16 full 64B
// lines (perfect utilization); W L2-hot; 16 waves/CU hide latency.
__global__ __launch_bounds__(256) void gemm1_k(const __hip_bfloat16* __restrict__ xbf,
                                               const __hip_bfloat16* __restrict__ wbf,
                                               const float* __restrict__ bmu,
                                               const float* __restrict__ bsigv,
                                               const float* __restrict__ eps,
                                               float* __restrict__ zout,
                                               __hip_bfloat16* __restrict__ Ac,
                                               __hip_bfloat16* __restrict__ Aq) {
  const int tid = threadIdx.x, lane = tid & 63, wv = tid >> 6;
  const int lrow = lane & 15, q = lane >> 4;
  const int m0 = blockIdx.x * 64 + wv * 16;
  const int d0 = blockIdx.y * 32;

  f32x4 acc[4];
  acc[0] = acc[1] = acc[2] = acc[3] = (f32x4){0.f, 0.f, 0.f, 0.f};

  const __hip_bfloat16* aB = xbf + (size_t)(m0 + lrow) * ND + q * 8;
  const __hip_bfloat16* bB[4];
  #pragma unroll
  for (int nf = 0; nf < 4; ++nf) {
    int wrow = (nf >> 1) * 256 + d0 + (nf & 1) * 16 + lrow;
    bB[nf] = wbf + (size_t)wrow * ND + q * 8;
  }

  #pragma unroll
  for (int ks = 0; ks < 8; ++ks) {
    const int kc = ks * 32;
    short8 a = *reinterpret_cast<const short8*>(aB + kc);
    #pragma unroll
    for (int nf = 0; nf < 4; ++nf) {
      short8 b = *reinterpret_cast<const short8*>(bB[nf] + kc);
      acc[nf] = mfma_bf16(a, b, acc[nf]);
    }
  }

  // epilogue: C/D layout col=lane&15 (-> d/plane), row=q*4+j (-> b)
  #pragma unroll
  for (int dp = 0; dp < 2; ++dp) {
    const int d = d0 + dp * 16 + lrow;
    const float bm = bmu[d], bs = bsigv[d];
    #pragma unroll
    for (int j = 0; j < 4; ++j) {
      const int b = m0 + q * 4 + j;
      float muv = acc[dp][j] + bm;
      float lsv = acc[2 + dp][j] + bs;
      float sq  = __expf(lsv);
      float e   = eps[(size_t)b * ND + d];
      float zv  = muv + sqrtf(sq) * e;
      zout[(size_t)b * ND + d] = zv;
      size_t ro = (size_t)b * 512;
      Ac[ro + d]       = __float2bfloat16(zv * zv);
      Ac[ro + 256 + d] = __float2bfloat16(zv);
      Aq[ro + d]       = __float2bfloat16(sq + muv * muv);
      Aq[ro + 256 + d] = __float2bfloat16(muv);
    }
  }
}

// ---- kernel 2: cluster GEMMs + softmax + loss partials ---------------------
// 512 blocks x 256 thr (4 waves); block = 16 b-rows; wave wv = K-slice 128
// features (16 independent loads + 16 MFMAs). LDS reduce over 4 waves, then
// 16-lane-group softmax. part layout TRANSPOSED: part[c][512], c=0..32.
__global__ __launch_bounds__(256) void cluster2_k(const __hip_bfloat16* __restrict__ Ac,
                                                  const __hip_bfloat16* __restrict__ Aq,
                                                  const __hip_bfloat16* __restrict__ Bc,
                                                  const float* __restrict__ c3k,
                                                  const float* __restrict__ ckk,
                                                  float* __restrict__ part) {
  __shared__ float sW[4][2][16][33];   // padded: conflict-free
  __shared__ float piP[NK];
  __shared__ float gSum;
  const int tid = threadIdx.x, lane = tid & 63, wv = tid >> 6;
  const int lrow = lane & 15, q = lane >> 4;
  const int m0 = blockIdx.x * 16;
  const int f0 = wv * 128;

  if (tid < NK) piP[tid] = 0.f;
  if (tid == 0) gSum = 0.f;

  f32x4 cL[2], cQ[2];
  cL[0] = cL[1] = cQ[0] = cQ[1] = (f32x4){0.f, 0.f, 0.f, 0.f};

  const __hip_bfloat16* arc = Ac + (size_t)(m0 + lrow) * 512 + f0 + q * 8;
  const __hip_bfloat16* arq = Aq + (size_t)(m0 + lrow) * 512 + f0 + q * 8;
  const __hip_bfloat16* br0 = Bc + (size_t)lrow * 512 + f0 + q * 8;
  const __hip_bfloat16* br1 = Bc + (size_t)(16 + lrow) * 512 + f0 + q * 8;

  #pragma unroll
  for (int ks = 0; ks < 4; ++ks) {
    const int kc = ks * 32;
    short8 ac = *reinterpret_cast<const short8*>(arc + kc);
    short8 aq = *reinterpret_cast<const short8*>(arq + kc);
    short8 b0 = *reinterpret_cast<const short8*>(br0 + kc);
    short8 b1 = *reinterpret_cast<const short8*>(br1 + kc);
    cL[0] = mfma_bf16(ac, b0, cL[0]);
    cL[1] = mfma_bf16(ac, b1, cL[1]);
    cQ[0] = mfma_bf16(aq, b0, cQ[0]);
    cQ[1] = mfma_bf16(aq, b1, cQ[1]);
  }

  #pragma unroll
  for (int nfk = 0; nfk < 2; ++nfk)
    #pragma unroll
    for (int j = 0; j < 4; ++j) {
      sW[wv][0][q * 4 + j][nfk * 16 + lrow] = cL[nfk][j];
      sW[wv][1][q * 4 + j][nfk * 16 + lrow] = cQ[nfk][j];
    }
  __syncthreads();

  // epilogue: 256 thr; b = tid>>4 (0..15), kk = tid&15 (16-lane shuffle group)
  {
    const int b = tid >> 4, kk = tid & 15;
    float L0 = sW[0][0][b][kk]      + sW[1][0][b][kk]      + sW[2][0][b][kk]      + sW[3][0][b][kk];
    float L1 = sW[0][0][b][kk + 16] + sW[1][0][b][kk + 16] + sW[2][0][b][kk + 16] + sW[3][0][b][kk + 16];
    float Q0 = sW[0][1][b][kk]      + sW[1][1][b][kk]      + sW[2][1][b][kk]      + sW[3][1][b][kk];
    float Q1 = sW[0][1][b][kk + 16] + sW[1][1][b][kk + 16] + sW[2][1][b][kk + 16] + sW[3][1][b][kk + 16];
    float l0 = -(L0 + c3k[kk]);
    float l1 = -(L1 + c3k[kk + 16]);
    float mx = fmaxf(l0, l1);
    #pragma unroll
    for (int s = 8; s; s >>= 1) mx = fmaxf(mx, __shfl_xor(mx, s));
    float p0 = __expf(l0 - mx), p1 = __expf(l1 - mx);
    float ps = p0 + p1;
    #pragma unroll
    for (int s = 8; s; s >>= 1) ps += __shfl_xor(ps, s);
    float pi0 = p0 / ps + 1e-10f;
    float pi1 = p1 / ps + 1e-10f;
    float g = pi0 * (Q0 + ckk[kk]) + pi1 * (Q1 + ckk[kk + 16]);
    #pragma unroll
    for (int s = 8; s; s >>= 1) g += __shfl_xor(g, s);
    atomicAdd(&piP[kk], pi0);
    atomicAdd(&piP[kk + 16], pi1);
    if (kk == 0) atomicAdd(&gSum, g);
  }
  __syncthreads();
  if (tid < NK) part[(size_t)tid * 512 + blockIdx.x] = piP[tid];
  if (tid == NK) part[(size_t)NK * 512 + blockIdx.x] = 0.5f * gSum;
}

// ---- kernel 3: final reduce (part[33][512], float4 rows, 4-way wave split) -
__global__ __launch_bounds__(256) void final_k(const float* __restrict__ part,
                                               float* __restrict__ out) {
  __shared__ double red[4][33];
  const int tid = threadIdx.x, lane = tid & 63, wv = tid >> 6;
  if (lane < 33) {
    const float4* p4 = reinterpret_cast<const float4*>(part + (size_t)lane * 512);
    double acc = 0.0;
    for (int i = wv * 32; i < wv * 32 + 32; ++i) {
      float4 v = p4[i];
      acc += (double)v.x + (double)v.y + (double)v.z + (double)v.w;
    }
    red[wv][lane] = acc;
  }
  __syncthreads();
  if (tid >= 64) return;
  double s = (tid < 33) ? (red[0][tid] + red[1][tid] + red[2][tid] + red[3][tid]) : 0.0;
  if (tid == 32) out[NB * ND] = (float)s;            // batch_gaussian_loss
  double t = 0.0;
  if (tid < 32) { double mk = s / (double)NB; t = mk * log(mk); }
  #pragma unroll
  for (int sh = 16; sh; sh >>= 1) t += __shfl_xor(t, sh);
  if (tid == 0) out[NB * ND + 1] = (float)(t / (double)NK);
}

extern "C" void kernel_launch(void* const* d_in, const int* in_sizes, int n_in,
                              void* d_out, int out_size, void* d_ws, size_t ws_size,
                              hipStream_t stream) {
  const float* x    = (const float*)d_in[0];
  const float* eps  = (const float*)d_in[1];
  const float* wmu  = (const float*)d_in[2];
  const float* bmu  = (const float*)d_in[3];
  const float* wsig = (const float*)d_in[4];
  const float* bsig = (const float*)d_in[5];
  const float* mu_c = (const float*)d_in[6];
  const float* lsc  = (const float*)d_in[7];
  float* out = (float*)d_out;

  char* ws = (char*)d_ws;
  __hip_bfloat16* xbf = (__hip_bfloat16*)ws;                               // 4 MiB
  __hip_bfloat16* Ac  = (__hip_bfloat16*)(ws + (4u << 20));                // 8 MiB
  __hip_bfloat16* Aq  = (__hip_bfloat16*)(ws + (12u << 20));               // 8 MiB
  __hip_bfloat16* wbf = (__hip_bfloat16*)(ws + (20u << 20));               // 256 KiB
  __hip_bfloat16* Bc  = (__hip_bfloat16*)(ws + (20u << 20) + (256u << 10)); // 32 KiB
  float* c3k  = (float*)(ws + (20u << 20) + (288u << 10));                 // 128 B
  float* ckk  = (float*)(ws + (20u << 20) + (288u << 10) + 256u);          // 128 B
  float* part = (float*)(ws + (20u << 20) + (288u << 10) + 512u);          // 66 KiB

  prep_k<<<2592, 256, 0, stream>>>((const float4*)x, (ushort4*)xbf,
                                   wmu, wsig, wbf, mu_c, lsc, Bc, c3k, ckk);
  gemm1_k<<<dim3(128, 8), 256, 0, stream>>>(xbf, wbf, bmu, bsig, eps, out, Ac, Aq);
  cluster2_k<<<512, 256, 0, stream>>>(Ac, Aq, Bc, c3k, ckk, part);
  final_k<<<1, 256, 0, stream>>>(part, out);
}

// Round 5
// 39.831 us; speedup vs baseline: 1.3967x; 1.1769x over previous
//
#include <hip/hip_runtime.h>
#include <hip/hip_bf16.h>

typedef __attribute__((ext_vector_type(4))) float f32x4;
typedef __attribute__((ext_vector_type(8))) short short8;

#define NB 8192
#define ND 256
#define NK 32
#define PADF 520  // AcT/AqT row stride (ushort): 1040B, 16B-aligned

static __device__ __forceinline__ unsigned short f2bf(float f) {
  return __builtin_bit_cast(unsigned short, __float2bfloat16(f));
}

static __device__ __forceinline__ f32x4 mfma_bf16(short8 a, short8 b, f32x4 c) {
  return __builtin_amdgcn_mfma_f32_16x16x32_bf16(a, b, c, 0, 0, 0);
}

static __device__ __forceinline__ short8 pack_bf16x8(float4 lo, float4 hi) {
  short8 r;
  r[0] = (short)f2bf(lo.x); r[1] = (short)f2bf(lo.y);
  r[2] = (short)f2bf(lo.z); r[3] = (short)f2bf(lo.w);
  r[4] = (short)f2bf(hi.x); r[5] = (short)f2bf(hi.y);
  r[6] = (short)f2bf(hi.z); r[7] = (short)f2bf(hi.w);
  return r;
}

// ---- kernel 0: small prep ---------------------------------------------------
// blocks [0,512)   : Wcat = [W_mu; W_sig] -> bf16 [512][256]
// blocks [512,544) : Bc bf16 [32][512]: Bc[k][d]=exp(-lsc), Bc[k][256+d]=-2*mu_c*exp(-lsc)
//                    c3k[k]=sum mu_c^2*inv ; ckk[k]=sum lsc + c3k[k]
__global__ __launch_bounds__(256) void prep_k(const float* __restrict__ wmu,
                                              const float* __restrict__ wsig,
                                              __hip_bfloat16* __restrict__ wb,
                                              const float* __restrict__ mu_c,
                                              const float* __restrict__ lsc,
                                              __hip_bfloat16* __restrict__ Bc,
                                              float* __restrict__ c3k,
                                              float* __restrict__ ckk) {
  __shared__ float red1[4], red2[4];
  const int blk = blockIdx.x, tid = threadIdx.x;
  if (blk < 512) {
    int i = blk * 256 + tid;
    float v = (i < 65536) ? wmu[i] : wsig[i - 65536];
    wb[i] = __float2bfloat16(v);
  } else {
    int k = blk - 512;
    int d = tid;
    float l = lsc[k * ND + d];
    float inv = __expf(-l);
    float mc = mu_c[k * ND + d];
    Bc[k * 512 + d]       = __float2bfloat16(inv);
    Bc[k * 512 + 256 + d] = __float2bfloat16(-2.f * mc * inv);
    float s1 = l, s2 = mc * mc * inv;
    #pragma unroll
    for (int sh = 32; sh; sh >>= 1) { s1 += __shfl_xor(s1, sh); s2 += __shfl_xor(s2, sh); }
    int lane = tid & 63, wv = tid >> 6;
    if (lane == 0) { red1[wv] = s1; red2[wv] = s2; }
    __syncthreads();
    if (tid == 0) {
      float t1 = red1[0] + red1[1] + red1[2] + red1[3];
      float t2 = red2[0] + red2[1] + red2[2] + red2[3];
      c3k[k] = t2;
      ckk[k] = t1 + t2;
    }
  }
}

// ---- kernel 1: mega-fused per 16-row b-tile --------------------------------
// 512 blocks x 256 thr (4 waves), 2 blocks/CU. Block owns b-rows [m0,m0+16).
// Phase 1 (GEMM1): wave w owns d-slice [w*64, w*64+64), both mu & sig planes.
//   A: x read DIRECT as f32, converted to bf16 in-register (no xbf round trip).
//   B: Wcat bf16 from global (L2-hot, 256 KiB). No LDS, no barrier.
//   acc[dp][plane]: d = w*64+dp*16+lrow; plane 0=mu, 1=sig.
// Epilogue 1: z -> d_out; bf16 [z^2|z] -> AcT, [sq+mu^2|mu] -> AqT (LDS).
// Phase 2 (cluster): wave w takes feature K-slice [w*128, w*128+128):
//   16 LDS A-frag reads + 16 global B-frag reads + 16 MFMAs; LDS reduce;
//   16-lane-group softmax; block partials -> part[33][512] (transposed).
__global__ __launch_bounds__(256, 3) void mega_k(const float* __restrict__ xf,
                                                 const __hip_bfloat16* __restrict__ wbf,
                                                 const float* __restrict__ bmu,
                                                 const float* __restrict__ bsigv,
                                                 const float* __restrict__ eps,
                                                 const __hip_bfloat16* __restrict__ Bc,
                                                 const float* __restrict__ c3k,
                                                 const float* __restrict__ ckk,
                                                 float* __restrict__ zout,
                                                 float* __restrict__ part) {
  __shared__ __align__(16) unsigned short AcT[16][PADF];
  __shared__ __align__(16) unsigned short AqT[16][PADF];
  __shared__ float sW[4][2][16][33];
  __shared__ float piP[NK];
  __shared__ float gSum;

  const int tid = threadIdx.x, lane = tid & 63, w = tid >> 6;
  const int lrow = lane & 15, q = lane >> 4;
  const int m0 = blockIdx.x * 16;

  if (tid < NK) piP[tid] = 0.f;
  if (tid == 0) gSum = 0.f;

  // ---------------- phase 1: GEMM1 (direct-global operands) ----------------
  f32x4 acc[4][2];
  #pragma unroll
  for (int a = 0; a < 4; ++a) { acc[a][0] = (f32x4){0,0,0,0}; acc[a][1] = (f32x4){0,0,0,0}; }

  const float* aB = xf + (size_t)(m0 + lrow) * ND + q * 8;
  const __hip_bfloat16* bB[8];
  #pragma unroll
  for (int nf = 0; nf < 8; ++nf) {
    int wrow = (nf & 1) * 256 + w * 64 + (nf >> 1) * 16 + lrow;
    bB[nf] = wbf + (size_t)wrow * ND + q * 8;
  }

  #pragma unroll
  for (int ks = 0; ks < 8; ++ks) {
    const int kc = ks * 32;
    float4 alo = *reinterpret_cast<const float4*>(aB + kc);
    float4 ahi = *reinterpret_cast<const float4*>(aB + kc + 4);
    short8 a = pack_bf16x8(alo, ahi);
    #pragma unroll
    for (int nf = 0; nf < 8; ++nf) {
      short8 b = *reinterpret_cast<const short8*>(bB[nf] + kc);
      acc[nf >> 1][nf & 1] = mfma_bf16(a, b, acc[nf >> 1][nf & 1]);
    }
  }

  // ---------------- epilogue 1: z + LDS deposit ----------------
  #pragma unroll
  for (int dp = 0; dp < 4; ++dp) {
    const int d = w * 64 + dp * 16 + lrow;
    const float bm = bmu[d], bs = bsigv[d];
    #pragma unroll
    for (int j = 0; j < 4; ++j) {
      const int bl = q * 4 + j;
      const int b = m0 + bl;
      float muv = acc[dp][0][j] + bm;
      float lsv = acc[dp][1][j] + bs;
      float sq  = __expf(lsv);
      float e   = eps[(size_t)b * ND + d];
      float zv  = muv + sqrtf(sq) * e;
      zout[(size_t)b * ND + d] = zv;
      AcT[bl][d]       = f2bf(zv * zv);
      AcT[bl][256 + d] = f2bf(zv);
      AqT[bl][d]       = f2bf(sq + muv * muv);
      AqT[bl][256 + d] = f2bf(muv);
    }
  }
  __syncthreads();

  // ---------------- phase 2: cluster GEMMs (K-slice per wave) ----------------
  f32x4 cL[2], cQ[2];
  cL[0] = cL[1] = cQ[0] = cQ[1] = (f32x4){0,0,0,0};
  const int f0 = w * 128;
  #pragma unroll
  for (int ks = 0; ks < 4; ++ks) {
    const int kc = f0 + ks * 32 + q * 8;
    short8 ac = *reinterpret_cast<const short8*>(&AcT[lrow][kc]);
    short8 aq = *reinterpret_cast<const short8*>(&AqT[lrow][kc]);
    short8 b0 = *reinterpret_cast<const short8*>(Bc + (size_t)lrow * 512 + kc);
    short8 b1 = *reinterpret_cast<const short8*>(Bc + (size_t)(16 + lrow) * 512 + kc);
    cL[0] = mfma_bf16(ac, b0, cL[0]);
    cL[1] = mfma_bf16(ac, b1, cL[1]);
    cQ[0] = mfma_bf16(aq, b0, cQ[0]);
    cQ[1] = mfma_bf16(aq, b1, cQ[1]);
  }
  #pragma unroll
  for (int nfk = 0; nfk < 2; ++nfk)
    #pragma unroll
    for (int j = 0; j < 4; ++j) {
      sW[w][0][q * 4 + j][nfk * 16 + lrow] = cL[nfk][j];
      sW[w][1][q * 4 + j][nfk * 16 + lrow] = cQ[nfk][j];
    }
  __syncthreads();

  // ---------------- epilogue 2: softmax + loss partials ----------------
  {
    const int b = tid >> 4, kk = tid & 15;
    float L0 = sW[0][0][b][kk]      + sW[1][0][b][kk]      + sW[2][0][b][kk]      + sW[3][0][b][kk];
    float L1 = sW[0][0][b][kk + 16] + sW[1][0][b][kk + 16] + sW[2][0][b][kk + 16] + sW[3][0][b][kk + 16];
    float Q0 = sW[0][1][b][kk]      + sW[1][1][b][kk]      + sW[2][1][b][kk]      + sW[3][1][b][kk];
    float Q1 = sW[0][1][b][kk + 16] + sW[1][1][b][kk + 16] + sW[2][1][b][kk + 16] + sW[3][1][b][kk + 16];
    float l0 = -(L0 + c3k[kk]);
    float l1 = -(L1 + c3k[kk + 16]);
    float mx = fmaxf(l0, l1);
    #pragma unroll
    for (int s = 8; s; s >>= 1) mx = fmaxf(mx, __shfl_xor(mx, s));
    float p0 = __expf(l0 - mx), p1 = __expf(l1 - mx);
    float ps = p0 + p1;
    #pragma unroll
    for (int s = 8; s; s >>= 1) ps += __shfl_xor(ps, s);
    float pi0 = p0 / ps + 1e-10f;
    float pi1 = p1 / ps + 1e-10f;
    float g = pi0 * (Q0 + ckk[kk]) + pi1 * (Q1 + ckk[kk + 16]);
    #pragma unroll
    for (int s = 8; s; s >>= 1) g += __shfl_xor(g, s);
    atomicAdd(&piP[kk], pi0);
    atomicAdd(&piP[kk + 16], pi1);
    if (kk == 0) atomicAdd(&gSum, g);
  }
  __syncthreads();
  if (tid < NK) part[(size_t)tid * 512 + blockIdx.x] = piP[tid];
  if (tid == NK) part[(size_t)NK * 512 + blockIdx.x] = 0.5f * gSum;
}

// ---- kernel 2: final reduce (part[33][512], float4 rows, 4-way wave split) -
__global__ __launch_bounds__(256) void final_k(const float* __restrict__ part,
                                               float* __restrict__ out) {
  __shared__ double red[4][33];
  const int tid = threadIdx.x, lane = tid & 63, wv = tid >> 6;
  if (lane < 33) {
    const float4* p4 = reinterpret_cast<const float4*>(part + (size_t)lane * 512);
    double acc = 0.0;
    for (int i = wv * 32; i < wv * 32 + 32; ++i) {
      float4 v = p4[i];
      acc += (double)v.x + (double)v.y + (double)v.z + (double)v.w;
    }
    red[wv][lane] = acc;
  }
  __syncthreads();
  if (tid >= 64) return;
  double s = (tid < 33) ? (red[0][tid] + red[1][tid] + red[2][tid] + red[3][tid]) : 0.0;
  if (tid == 32) out[NB * ND] = (float)s;            // batch_gaussian_loss
  double t = 0.0;
  if (tid < 32) { double mk = s / (double)NB; t = mk * log(mk); }
  #pragma unroll
  for (int sh = 16; sh; sh >>= 1) t += __shfl_xor(t, sh);
  if (tid == 0) out[NB * ND + 1] = (float)(t / (double)NK);
}

extern "C" void kernel_launch(void* const* d_in, const int* in_sizes, int n_in,
                              void* d_out, int out_size, void* d_ws, size_t ws_size,
                              hipStream_t stream) {
  const float* x    = (const float*)d_in[0];
  const float* eps  = (const float*)d_in[1];
  const float* wmu  = (const float*)d_in[2];
  const float* bmu  = (const float*)d_in[3];
  const float* wsig = (const float*)d_in[4];
  const float* bsig = (const float*)d_in[5];
  const float* mu_c = (const float*)d_in[6];
  const float* lsc  = (const float*)d_in[7];
  float* out = (float*)d_out;

  char* ws = (char*)d_ws;
  __hip_bfloat16* wbf = (__hip_bfloat16*)ws;                      // 256 KiB
  __hip_bfloat16* Bc  = (__hip_bfloat16*)(ws + (256u << 10));     // 32 KiB
  float* c3k  = (float*)(ws + (288u << 10));                      // 128 B
  float* ckk  = (float*)(ws + (288u << 10) + 256u);               // 128 B
  float* part = (float*)(ws + (288u << 10) + 512u);               // 66 KiB

  prep_k<<<544, 256, 0, stream>>>(wmu, wsig, wbf, mu_c, lsc, Bc, c3k, ckk);
  mega_k<<<512, 256, 0, stream>>>(x, wbf, bmu, bsig, eps, Bc, c3k, ckk, out, part);
  final_k<<<1, 256, 0, stream>>>(part, out);
}